// Round 14
// baseline (33.591 us; speedup 1.0000x reference)
//
#include <hip/hip_runtime.h>

// ---------------------------------------------------------------------------
// VQC_Net fully fused, SINGLE kernel: probs[b,c] = ((RY2 * D * RY1) amp)^2[c]
// R14: butterflies in MONOMIAL (tan/cot) form -> 2 FMA per pair (was 4 ops).
//   |c|>=|s|: [c,-s;s,c] = c*[1,-t;t,1], t=s/c  -> a0'=fma(-t,a1,a0), a1'=fma(t,a0,a1)
//   else:      = s*[u,-1;1,u], u=c/s            -> a0'=fma(u,a0,-a1), a1'=fma(u,a1,a0)
//   (neg = free VOP3 input modifier; divisor always >= 1/sqrt(2))
// Per-stage scalar factors accumulate into one uniform `scale`, folded into
// the amp build (linear chain; final square sees scale^2 automatically).
// ~184 VALU inst/thread-tile vs ~302 (R13) -> shorter compute bursts, store
// stream stays fed.
// Skeleton lessons kept: wave-private LDS staging, zero barriers (R8);
// NT stores, regular loads (R10/R11); front-loaded x reads (R12); LDS
// transpose essential (R7); no vmcnt-draining waits (R6); TILES=4, 2048 blk;
// fused single kernel (R13).
// amp build:
//   amp[0][k]  = prod_j ( (k>>j)&1 ? x0j : 1-x0j )                 (no sqrt)
//   amp[b][k]  = sqrt(hi)*sqrt(lo) factored, big-endian bits       (b >= 1)
// ---------------------------------------------------------------------------

typedef float f32x4 __attribute__((ext_vector_type(4)));

#if defined(__has_builtin)
#if __has_builtin(__builtin_amdgcn_sqrtf)
#define FSQRT(x) __builtin_amdgcn_sqrtf(x)
#endif
#endif
#ifndef FSQRT
#define FSQRT(x) sqrtf(x)
#endif

// amp for the generic (b>=1) path: big-endian bits, squared probs, sqrt.
// `scale` (uniform) is folded into the sh[] factors.
__device__ __forceinline__ void amp_resolve(f32x4 xv, float scale, float amp[16]) {
    float p0 = xv.x * xv.x, p1 = xv.y * xv.y;
    float p2 = xv.z * xv.z, p3 = xv.w * xv.w;
    float hi[4] = { (1.0f - p0) * (1.0f - p1), (1.0f - p0) * p1,
                    p0 * (1.0f - p1),          p0 * p1 };
    float lo[4] = { (1.0f - p2) * (1.0f - p3), (1.0f - p2) * p3,
                    p2 * (1.0f - p3),          p2 * p3 };
    float sh[4], sl[4];
#pragma unroll
    for (int i = 0; i < 4; ++i) { sh[i] = FSQRT(hi[i]) * scale; sl[i] = FSQRT(lo[i]); }
#pragma unroll
    for (int k = 0; k < 16; ++k)
        amp[k] = sh[k >> 2] * sl[k & 3];
}

// amp for sample 0: little-endian bits, raw products, no sqrt
__device__ __forceinline__ void amp_prob2amp(f32x4 xv, float scale, float amp[16]) {
    float lo[4] = { (1.0f - xv.x) * (1.0f - xv.y), xv.x * (1.0f - xv.y),
                    (1.0f - xv.x) * xv.y,          xv.x * xv.y };
    float hi[4] = { (1.0f - xv.z) * (1.0f - xv.w), xv.z * (1.0f - xv.w),
                    (1.0f - xv.z) * xv.w,          xv.z * xv.w };
#pragma unroll
    for (int k = 0; k < 16; ++k)
        amp[k] = (lo[k & 3] * scale) * hi[k >> 2];
}

#define TILES 4   // 4 x 256 samples per block; 2M / 1024 = 2048 blocks exact

__global__ __launch_bounds__(256, 8) void vqc_main(const f32x4* __restrict__ x,
                                                   const float* __restrict__ theta,
                                                   float* __restrict__ out,
                                                   int nsamp) {
    // wave-private double-buffered staging: [wave][buf][640 floats]
    __shared__ float sBuf[4][2][640];   // 20 KB

    int tid = threadIdx.x;
    int wid = tid >> 6;
    int lane = tid & 63;

    long long base = (long long)blockIdx.x * (TILES * 256);

    // FRONT-LOAD all 4 tiles of x (issued back-to-back; 4 outstanding vmem).
    f32x4 xv[TILES];
#pragma unroll
    for (int t = 0; t < TILES; ++t) {
        long long bt = base + (long long)t * 256 + tid;
        if (bt < nsamp) xv[t] = x[bt];
    }

    // Uniform butterfly coefficients: monomial form per stage.
    // stages 0..3 = RY1 qubits 0..3, stages 4..7 = RY2 qubits 0..3.
    float w[8];
    bool  ut[8];
    float scale = 1.0f;
#pragma unroll
    for (int q = 0; q < 8; ++q) {
        float h = 0.5f * theta[q];
        float c = __cosf(h), s = __sinf(h);
        bool t = fabsf(c) >= fabsf(s);
        ut[q] = t;
        w[q]  = t ? (s / c) : (c / s);
        scale *= t ? c : s;
    }

#pragma unroll
    for (int t = 0; t < TILES; ++t) {
        long long tileStart = base + (long long)t * 256;
        long long b = tileStart + tid;

        int p = t & 1;
        float* myBuf = sBuf[wid][p];

        if (b < nsamp) {
            float amp[16];
            if (b == 0) amp_prob2amp(xv[t], scale, amp);
            else        amp_resolve(xv[t], scale, amp);

            // ---- butterflies, monomial form: 2 FMA per pair ----
#define BFLY(Q, W, UT)                                                   \
            if (UT) {                                                    \
                _Pragma("unroll")                                        \
                for (int i0 = 0; i0 < 16; ++i0)                          \
                    if (!(i0 & (1 << (Q)))) {                            \
                        int i1 = i0 | (1 << (Q));                        \
                        float A = amp[i0], B = amp[i1];                  \
                        amp[i0] = fmaf(-(W), B, A);                      \
                        amp[i1] = fmaf((W), A, B);                       \
                    }                                                    \
            } else {                                                     \
                _Pragma("unroll")                                        \
                for (int i0 = 0; i0 < 16; ++i0)                          \
                    if (!(i0 & (1 << (Q)))) {                            \
                        int i1 = i0 | (1 << (Q));                        \
                        float A = amp[i0], B = amp[i1];                  \
                        amp[i0] = fmaf((W), A, -B);                      \
                        amp[i1] = fmaf((W), B, A);                       \
                    }                                                    \
            }

            BFLY(0, w[0], ut[0])   // RY1
            BFLY(1, w[1], ut[1])
            BFLY(2, w[2], ut[2])
            BFLY(3, w[3], ut[3])

            // D: sign flips at k = 3, 6, 9, 12
            amp[3]  = -amp[3];
            amp[6]  = -amp[6];
            amp[9]  = -amp[9];
            amp[12] = -amp[12];

            BFLY(0, w[4], ut[4])   // RY2 qubits 0..2
            BFLY(1, w[5], ut[5])
            BFLY(2, w[6], ut[6])
#undef BFLY

            // RY2 qubit-3 stage: only the 10 needed rows
            float r[10];
            if (ut[7]) {
#pragma unroll
                for (int i = 0; i < 8; ++i)
                    r[i] = fmaf(-w[7], amp[i + 8], amp[i]);
                r[8] = fmaf(w[7], amp[0], amp[8]);
                r[9] = fmaf(w[7], amp[1], amp[9]);
            } else {
#pragma unroll
                for (int i = 0; i < 8; ++i)
                    r[i] = fmaf(w[7], amp[i], -amp[i + 8]);
                r[8] = fmaf(w[7], amp[8], amp[0]);
                r[9] = fmaf(w[7], amp[9], amp[1]);
            }

#pragma unroll
            for (int c = 0; c < 10; ++c)
                myBuf[lane * 10 + c] = r[c] * r[c];   // 4-way bank alias: ~free
        }

        // drain OWN ds ops - intra-wave only, no barrier (wave-private slice)
        asm volatile("s_waitcnt lgkmcnt(0)" ::: "memory");

        long long waveBase = tileStart + (long long)(wid << 6);
        long long wrem = (long long)nsamp - waveBase;
        if (wrem >= 64) {
            // wave's 64 samples = 2560B contiguous in out, line-aligned.
            // NONTEMPORAL: out is write-once -> no-allocate, no L2/L3 churn.
            f32x4* ov = (f32x4*)(out + waveBase * 10);
            const f32x4* sv = (const f32x4*)myBuf;
#pragma unroll
            for (int i = lane; i < 160; i += 64)
                __builtin_nontemporal_store(sv[i], &ov[i]);
        } else if (wrem > 0) {
            int n = (int)wrem * 10;
            for (int i = lane; i < n; i += 64)
                out[waveBase * 10 + i] = myBuf[i];
        }
        // WAR on buffer p (reused at t+2): protected by the lgkmcnt(0) at
        // t+1, which drains this tile's flush ds_reads before t+2's writes.
    }
}

extern "C" void kernel_launch(void* const* d_in, const int* in_sizes, int n_in,
                              void* d_out, int out_size, void* d_ws, size_t ws_size,
                              hipStream_t stream) {
    const float* x = (const float*)d_in[0];      // [B,4] f32
    const float* theta = (const float*)d_in[1];  // [8]   f32
    float* out = (float*)d_out;                  // [B,10] f32

    int nsamp = in_sizes[0] / 4;
    int spb = TILES * 256;
    int blocks = (nsamp + spb - 1) / spb;
    vqc_main<<<blocks, 256, 0, stream>>>((const f32x4*)x, theta, out, nsamp);
}

// Round 15
// 24.859 us; speedup vs baseline: 1.3512x; 1.3512x over previous
//
#include <hip/hip_runtime.h>

// ---------------------------------------------------------------------------
// VQC_Net fully fused, SINGLE kernel: probs[b,c] = ((RY2 * D * RY1) amp)^2[c]
// R15 = R13 math (plain butterflies, compile-time-constant control flow)
// with ONE change: __launch_bounds__(256, 4) instead of (256, 8).
// R14 lesson: runtime-data-dependent branches get predicated (both paths
// execute) AND +16 live scalars over the 64-VGPR cap of (256,8) = scratch
// spills -> +10us. R13 itself sits at ~62-70 VGPR demand, i.e. ON the
// (256,8) cliff; (256,4) caps at 128 VGPR so the allocator breathes,
// occupancy degrades only to actual demand (~7 waves/SIMD), spills gone.
//   RY layer, qubit q, pair (i, i|1<<q): [c,-s; s,c]
//   D = diag sign: -1 exactly at k in {3, 6, 9, 12}
//   final stage computes only the 10 needed outputs.
// Skeleton lessons kept: wave-private LDS staging, zero barriers (R8);
// NT stores, regular loads (R10/R11); front-loaded x reads (R12); LDS
// transpose essential (R7: direct stride-40B stores = 10x line-request
// amplification); no vmcnt-draining waits (R6); TILES=4, 2048 blocks;
// fused single kernel, in-kernel fast-trig coefficients (R13).
// amp build:
//   amp[0][k]  = prod_j ( (k>>j)&1 ? x0j : 1-x0j )                 (no sqrt)
//   amp[b][k]  = sqrt(hi)*sqrt(lo) factored, big-endian bits       (b >= 1)
// ---------------------------------------------------------------------------

typedef float f32x4 __attribute__((ext_vector_type(4)));

#if defined(__has_builtin)
#if __has_builtin(__builtin_amdgcn_sqrtf)
#define FSQRT(x) __builtin_amdgcn_sqrtf(x)
#endif
#endif
#ifndef FSQRT
#define FSQRT(x) sqrtf(x)
#endif

// amp for the generic (b>=1) path: big-endian bits, squared probs, sqrt
__device__ __forceinline__ void amp_resolve(f32x4 xv, float amp[16]) {
    float p0 = xv.x * xv.x, p1 = xv.y * xv.y;
    float p2 = xv.z * xv.z, p3 = xv.w * xv.w;
    float hi[4] = { (1.0f - p0) * (1.0f - p1), (1.0f - p0) * p1,
                    p0 * (1.0f - p1),          p0 * p1 };
    float lo[4] = { (1.0f - p2) * (1.0f - p3), (1.0f - p2) * p3,
                    p2 * (1.0f - p3),          p2 * p3 };
    float sh[4], sl[4];
#pragma unroll
    for (int i = 0; i < 4; ++i) { sh[i] = FSQRT(hi[i]); sl[i] = FSQRT(lo[i]); }
#pragma unroll
    for (int k = 0; k < 16; ++k)
        amp[k] = sh[k >> 2] * sl[k & 3];
}

// amp for sample 0: little-endian bits, raw products, no sqrt
__device__ __forceinline__ void amp_prob2amp(f32x4 xv, float amp[16]) {
    float lo[4] = { (1.0f - xv.x) * (1.0f - xv.y), xv.x * (1.0f - xv.y),
                    (1.0f - xv.x) * xv.y,          xv.x * xv.y };
    float hi[4] = { (1.0f - xv.z) * (1.0f - xv.w), xv.z * (1.0f - xv.w),
                    (1.0f - xv.z) * xv.w,          xv.z * xv.w };
#pragma unroll
    for (int k = 0; k < 16; ++k)
        amp[k] = lo[k & 3] * hi[k >> 2];
}

#define TILES 4   // 4 x 256 samples per block; 2M / 1024 = 2048 blocks exact

__global__ __launch_bounds__(256, 4) void vqc_main(const f32x4* __restrict__ x,
                                                   const float* __restrict__ theta,
                                                   float* __restrict__ out,
                                                   int nsamp) {
    // wave-private double-buffered staging: [wave][buf][640 floats]
    __shared__ float sBuf[4][2][640];   // 20 KB

    int tid = threadIdx.x;
    int wid = tid >> 6;
    int lane = tid & 63;

    long long base = (long long)blockIdx.x * (TILES * 256);

    // FRONT-LOAD all 4 tiles of x (issued back-to-back; 4 outstanding vmem).
    f32x4 xv[TILES];
#pragma unroll
    for (int t = 0; t < TILES; ++t) {
        long long bt = base + (long long)t * 256 + tid;
        if (bt < nsamp) xv[t] = x[bt];
    }

    // 16 uniform butterfly coefficients (theta uniform -> s_load; fast trig
    // hides under the outstanding x loads). One-time cost, amortized 4 tiles.
    float c1[4], s1[4], c2[4], s2[4];
#pragma unroll
    for (int q = 0; q < 4; ++q) {
        float h1 = 0.5f * theta[q];
        float h2 = 0.5f * theta[4 + q];
        c1[q] = __cosf(h1); s1[q] = __sinf(h1);
        c2[q] = __cosf(h2); s2[q] = __sinf(h2);
    }

#pragma unroll
    for (int t = 0; t < TILES; ++t) {
        long long tileStart = base + (long long)t * 256;
        long long b = tileStart + tid;

        int p = t & 1;
        float* myBuf = sBuf[wid][p];

        if (b < nsamp) {
            float amp[16];
            if (b == 0) amp_prob2amp(xv[t], amp);
            else        amp_resolve(xv[t], amp);

            // ---- U = RY2 * D * RY1 as butterflies (compile-time control) ----
#define BFLY(Q, CC, SS)                                                  \
            _Pragma("unroll")                                            \
            for (int i0 = 0; i0 < 16; ++i0)                              \
                if (!(i0 & (1 << (Q)))) {                                \
                    int i1 = i0 | (1 << (Q));                            \
                    float a0 = amp[i0], a1 = amp[i1];                    \
                    amp[i0] = fmaf((CC), a0, -(SS) * a1);                \
                    amp[i1] = fmaf((SS), a0,  (CC) * a1);                \
                }

            BFLY(0, c1[0], s1[0])
            BFLY(1, c1[1], s1[1])
            BFLY(2, c1[2], s1[2])
            BFLY(3, c1[3], s1[3])

            // D: sign flips at k = 3, 6, 9, 12
            amp[3]  = -amp[3];
            amp[6]  = -amp[6];
            amp[9]  = -amp[9];
            amp[12] = -amp[12];

            BFLY(0, c2[0], s2[0])
            BFLY(1, c2[1], s2[1])
            BFLY(2, c2[2], s2[2])
#undef BFLY

            // qubit-3 stage: only the 10 needed rows
            float r[10];
#pragma unroll
            for (int i = 0; i < 8; ++i)
                r[i] = fmaf(c2[3], amp[i], -s2[3] * amp[i + 8]);
            r[8] = fmaf(s2[3], amp[0], c2[3] * amp[8]);
            r[9] = fmaf(s2[3], amp[1], c2[3] * amp[9]);

#pragma unroll
            for (int c = 0; c < 10; ++c)
                myBuf[lane * 10 + c] = r[c] * r[c];   // 4-way bank alias: ~free
        }

        // drain OWN ds ops - intra-wave only, no barrier (wave-private slice)
        asm volatile("s_waitcnt lgkmcnt(0)" ::: "memory");

        long long waveBase = tileStart + (long long)(wid << 6);
        long long wrem = (long long)nsamp - waveBase;
        if (wrem >= 64) {
            // wave's 64 samples = 2560B contiguous in out, line-aligned.
            // NONTEMPORAL: out is write-once -> no-allocate, no L2/L3 churn.
            f32x4* ov = (f32x4*)(out + waveBase * 10);
            const f32x4* sv = (const f32x4*)myBuf;
#pragma unroll
            for (int i = lane; i < 160; i += 64)
                __builtin_nontemporal_store(sv[i], &ov[i]);
        } else if (wrem > 0) {
            int n = (int)wrem * 10;
            for (int i = lane; i < n; i += 64)
                out[waveBase * 10 + i] = myBuf[i];
        }
        // WAR on buffer p (reused at t+2): protected by the lgkmcnt(0) at
        // t+1, which drains this tile's flush ds_reads before t+2's writes.
    }
}

extern "C" void kernel_launch(void* const* d_in, const int* in_sizes, int n_in,
                              void* d_out, int out_size, void* d_ws, size_t ws_size,
                              hipStream_t stream) {
    const float* x = (const float*)d_in[0];      // [B,4] f32
    const float* theta = (const float*)d_in[1];  // [8]   f32
    float* out = (float*)d_out;                  // [B,10] f32

    int nsamp = in_sizes[0] / 4;
    int spb = TILES * 256;
    int blocks = (nsamp + spb - 1) / spb;
    vqc_main<<<blocks, 256, 0, stream>>>((const f32x4*)x, theta, out, nsamp);
}

// Round 16
// 22.638 us; speedup vs baseline: 1.4838x; 1.0981x over previous
//
#include <hip/hip_runtime.h>

// ---------------------------------------------------------------------------
// VQC_Net fully fused, SINGLE kernel: probs[b,c] = ((RY2 * D * RY1) amp)^2[c]
// R16 = R13 skeleton + monomial butterflies done RIGHT:
//   |c|>=|s| (tan):  [c,-s;s,c] = c*[1,-t;t,1], t=s/c
//        a0' = fmaf(-t, a1, a0);  a1' = fmaf(t, a0, a1)     (2 FMA/pair)
//   else (cot):      [c,-s;s,c] = s*[u,-1;1,u], u=c/s
//        a0' = fmaf(u, a0, -a1);  a1' = fmaf(u, a1, a0)     (2 FMA/pair)
// Scalar factors (c or s per stage) accumulate into uniform `scale`, folded
// into the amp build (chain is linear; final square handles scale^2).
// R14 lessons fixed: form flags + w coeffs are READFIRSTLANE'd -> SGPRs ->
// s_cbranch uniform branches (one path executes, no predication) and ZERO
// added VGPR pressure; stays (256,8) like R13 (R15: 8th wave worth ~1us).
// Skeleton lessons kept: wave-private LDS staging, zero barriers (R8);
// NT stores, regular loads (R10/R11); front-loaded x reads (R12); LDS
// transpose essential (R7); no vmcnt-draining waits (R6); TILES=4, 2048 blk;
// fused single kernel, in-kernel fast-trig coefficients (R13).
// amp build:
//   amp[0][k]  = prod_j ( (k>>j)&1 ? x0j : 1-x0j )                 (no sqrt)
//   amp[b][k]  = sqrt(hi)*sqrt(lo) factored, big-endian bits       (b >= 1)
// ---------------------------------------------------------------------------

typedef float f32x4 __attribute__((ext_vector_type(4)));

#if defined(__has_builtin)
#if __has_builtin(__builtin_amdgcn_sqrtf)
#define FSQRT(x) __builtin_amdgcn_sqrtf(x)
#endif
#endif
#ifndef FSQRT
#define FSQRT(x) sqrtf(x)
#endif

// force a wave-uniform value into an SGPR (compiler then emits s_cbranch /
// SGPR-operand VALU instead of predication / VGPR duplication)
__device__ __forceinline__ float rfl(float v) {
    return __int_as_float(__builtin_amdgcn_readfirstlane(__float_as_int(v)));
}
__device__ __forceinline__ int rfl(int v) {
    return __builtin_amdgcn_readfirstlane(v);
}

// amp for the generic (b>=1) path: big-endian bits, squared probs, sqrt.
// uniform `scale` folded into sh[].
__device__ __forceinline__ void amp_resolve(f32x4 xv, float scale, float amp[16]) {
    float p0 = xv.x * xv.x, p1 = xv.y * xv.y;
    float p2 = xv.z * xv.z, p3 = xv.w * xv.w;
    float hi[4] = { (1.0f - p0) * (1.0f - p1), (1.0f - p0) * p1,
                    p0 * (1.0f - p1),          p0 * p1 };
    float lo[4] = { (1.0f - p2) * (1.0f - p3), (1.0f - p2) * p3,
                    p2 * (1.0f - p3),          p2 * p3 };
    float sh[4], sl[4];
#pragma unroll
    for (int i = 0; i < 4; ++i) { sh[i] = FSQRT(hi[i]) * scale; sl[i] = FSQRT(lo[i]); }
#pragma unroll
    for (int k = 0; k < 16; ++k)
        amp[k] = sh[k >> 2] * sl[k & 3];
}

// amp for sample 0: little-endian bits, raw products, no sqrt
__device__ __forceinline__ void amp_prob2amp(f32x4 xv, float scale, float amp[16]) {
    float lo[4] = { (1.0f - xv.x) * (1.0f - xv.y), xv.x * (1.0f - xv.y),
                    (1.0f - xv.x) * xv.y,          xv.x * xv.y };
    float hi[4] = { (1.0f - xv.z) * (1.0f - xv.w), xv.z * (1.0f - xv.w),
                    (1.0f - xv.z) * xv.w,          xv.z * xv.w };
#pragma unroll
    for (int k = 0; k < 16; ++k)
        amp[k] = (lo[k & 3] * scale) * hi[k >> 2];
}

#define TILES 4   // 4 x 256 samples per block; 2M / 1024 = 2048 blocks exact

__global__ __launch_bounds__(256, 8) void vqc_main(const f32x4* __restrict__ x,
                                                   const float* __restrict__ theta,
                                                   float* __restrict__ out,
                                                   int nsamp) {
    // wave-private double-buffered staging: [wave][buf][640 floats]
    __shared__ float sBuf[4][2][640];   // 20 KB -> 8 blocks/CU = 160 KiB exact

    int tid = threadIdx.x;
    int wid = tid >> 6;
    int lane = tid & 63;

    long long base = (long long)blockIdx.x * (TILES * 256);

    // FRONT-LOAD all 4 tiles of x (issued back-to-back; 4 outstanding vmem).
    f32x4 xv[TILES];
#pragma unroll
    for (int t = 0; t < TILES; ++t) {
        long long bt = base + (long long)t * 256 + tid;
        if (bt < nsamp) xv[t] = x[bt];
    }

    // Uniform monomial coefficients, scalarized into SGPRs.
    // stages 0..3 = RY1 qubits 0..3, stages 4..7 = RY2 qubits 0..3.
    float w[8];
    int   ct[8];          // 1 = cot form (|s| > |c|), 0 = tan form
    float scale = 1.0f;
#pragma unroll
    for (int q = 0; q < 8; ++q) {
        float h = 0.5f * theta[q];
        float c = __cosf(h), s = __sinf(h);
        int cot = rfl(fabsf(s) > fabsf(c) ? 1 : 0);
        ct[q] = cot;
        w[q]  = rfl(cot ? (c / s) : (s / c));
        scale *= cot ? s : c;
    }
    scale = rfl(scale);

#pragma unroll
    for (int t = 0; t < TILES; ++t) {
        long long tileStart = base + (long long)t * 256;
        long long b = tileStart + tid;

        int p = t & 1;
        float* myBuf = sBuf[wid][p];

        if (b < nsamp) {
            float amp[16];
            if (b == 0) amp_prob2amp(xv[t], scale, amp);
            else        amp_resolve(xv[t], scale, amp);

            // ---- monomial butterflies: 2 FMA/pair, uniform s_cbranch ----
#define BFLY(Q, W, CT)                                                   \
            if (CT) {                                                    \
                _Pragma("unroll")                                        \
                for (int i0 = 0; i0 < 16; ++i0)                          \
                    if (!(i0 & (1 << (Q)))) {                            \
                        int i1 = i0 | (1 << (Q));                        \
                        float A = amp[i0], B = amp[i1];                  \
                        amp[i0] = fmaf((W), A, -B);                      \
                        amp[i1] = fmaf((W), B, A);                       \
                    }                                                    \
            } else {                                                     \
                _Pragma("unroll")                                        \
                for (int i0 = 0; i0 < 16; ++i0)                          \
                    if (!(i0 & (1 << (Q)))) {                            \
                        int i1 = i0 | (1 << (Q));                        \
                        float A = amp[i0], B = amp[i1];                  \
                        amp[i0] = fmaf(-(W), B, A);                      \
                        amp[i1] = fmaf((W), A, B);                       \
                    }                                                    \
            }

            BFLY(0, w[0], ct[0])   // RY1
            BFLY(1, w[1], ct[1])
            BFLY(2, w[2], ct[2])
            BFLY(3, w[3], ct[3])

            // D: sign flips at k = 3, 6, 9, 12
            amp[3]  = -amp[3];
            amp[6]  = -amp[6];
            amp[9]  = -amp[9];
            amp[12] = -amp[12];

            BFLY(0, w[4], ct[4])   // RY2 qubits 0..2
            BFLY(1, w[5], ct[5])
            BFLY(2, w[6], ct[6])
#undef BFLY

            // RY2 qubit-3 stage: only the 10 needed rows
            float r[10];
            if (ct[7]) {
#pragma unroll
                for (int i = 0; i < 8; ++i)
                    r[i] = fmaf(w[7], amp[i], -amp[i + 8]);
                r[8] = fmaf(w[7], amp[8], amp[0]);
                r[9] = fmaf(w[7], amp[9], amp[1]);
            } else {
#pragma unroll
                for (int i = 0; i < 8; ++i)
                    r[i] = fmaf(-w[7], amp[i + 8], amp[i]);
                r[8] = fmaf(w[7], amp[0], amp[8]);
                r[9] = fmaf(w[7], amp[1], amp[9]);
            }

#pragma unroll
            for (int c = 0; c < 10; ++c)
                myBuf[lane * 10 + c] = r[c] * r[c];   // 4-way bank alias: ~free
        }

        // drain OWN ds ops - intra-wave only, no barrier (wave-private slice)
        asm volatile("s_waitcnt lgkmcnt(0)" ::: "memory");

        long long waveBase = tileStart + (long long)(wid << 6);
        long long wrem = (long long)nsamp - waveBase;
        if (wrem >= 64) {
            // wave's 64 samples = 2560B contiguous in out, line-aligned.
            // NONTEMPORAL: out is write-once -> no-allocate, no L2/L3 churn.
            f32x4* ov = (f32x4*)(out + waveBase * 10);
            const f32x4* sv = (const f32x4*)myBuf;
#pragma unroll
            for (int i = lane; i < 160; i += 64)
                __builtin_nontemporal_store(sv[i], &ov[i]);
        } else if (wrem > 0) {
            int n = (int)wrem * 10;
            for (int i = lane; i < n; i += 64)
                out[waveBase * 10 + i] = myBuf[i];
        }
        // WAR on buffer p (reused at t+2): protected by the lgkmcnt(0) at
        // t+1, which drains this tile's flush ds_reads before t+2's writes.
    }
}

extern "C" void kernel_launch(void* const* d_in, const int* in_sizes, int n_in,
                              void* d_out, int out_size, void* d_ws, size_t ws_size,
                              hipStream_t stream) {
    const float* x = (const float*)d_in[0];      // [B,4] f32
    const float* theta = (const float*)d_in[1];  // [8]   f32
    float* out = (float*)d_out;                  // [B,10] f32

    int nsamp = in_sizes[0] / 4;
    int spb = TILES * 256;
    int blocks = (nsamp + spb - 1) / spb;
    vqc_main<<<blocks, 256, 0, stream>>>((const f32x4*)x, theta, out, nsamp);
}

// Round 17
// 22.238 us; speedup vs baseline: 1.5105x; 1.0180x over previous
//
#include <hip/hip_runtime.h>

// ---------------------------------------------------------------------------
// VQC_Net fully fused, SINGLE kernel: probs[b,c] = ((RY2 * D * RY1) amp)^2[c]
// R17 = R16 + PRODUCT-STATE FUSION of RY1:
//   amp = v3 (x) v2 (x) v1 (x) v0  (Kronecker of four 2-vectors), and
//   RY1 = ry3 (x) ry2 (x) ry1 (x) ry0, so RY1*amp = (x)_q (ry_q * v_q):
//   RY1's 64 butterfly FMAs collapse to 4 monomial 2-vector rotations (8 FMA)
//   applied BEFORE the outer-product amp build. D (entangling CZ diagonal)
//   and RY2 are not product-factorable -> stay as R16 monomial butterflies.
// Monomial form per stage (R16-proven, SGPR-uniform branch):
//   tan (|c|>=|s|): (a,b) -> (fmaf(-w,b,a), fmaf(w,a,b)), scale *= c
//   cot           : (a,b) -> (fmaf(w,a,-b), fmaf(w,b,a)), scale *= s
// Total uniform scale folded into v3; final square yields scale^2.
// Index mapping (verified == R16 tables):
//   resolve (b>=1, big-endian):  amp bit q <-> x qubit 3-q, v = [sqrt(1-p), sqrt(p)]
//   sample0 (little-endian):     amp bit q <-> x qubit q,   v = [1-x, x]
//   hi[h] = v3[h>>1]*v2[h&1], lo[l] = v1[l>>1]*v0[l&1], amp[k]=hi[k>>2]*lo[k&3]
// Skeleton lessons kept: wave-private LDS staging, zero barriers (R8);
// NT stores, regular loads (R10/R11); front-loaded x reads (R12); LDS
// transpose essential (R7); no vmcnt-draining waits (R6); TILES=4, 2048 blk;
// fused single kernel + in-kernel fast trig (R13); (256,8) (R15: 8th wave
// worth ~1us); SGPR-uniform monomial control (R16).
// ---------------------------------------------------------------------------

typedef float f32x4 __attribute__((ext_vector_type(4)));

#if defined(__has_builtin)
#if __has_builtin(__builtin_amdgcn_sqrtf)
#define FSQRT(x) __builtin_amdgcn_sqrtf(x)
#endif
#endif
#ifndef FSQRT
#define FSQRT(x) sqrtf(x)
#endif

__device__ __forceinline__ float rfl(float v) {
    return __int_as_float(__builtin_amdgcn_readfirstlane(__float_as_int(v)));
}
__device__ __forceinline__ int rfl(int v) {
    return __builtin_amdgcn_readfirstlane(v);
}

#define TILES 4   // 4 x 256 samples per block; 2M / 1024 = 2048 blocks exact

__global__ __launch_bounds__(256, 8) void vqc_main(const f32x4* __restrict__ x,
                                                   const float* __restrict__ theta,
                                                   float* __restrict__ out,
                                                   int nsamp) {
    // wave-private double-buffered staging: [wave][buf][640 floats]
    __shared__ float sBuf[4][2][640];   // 20 KB

    int tid = threadIdx.x;
    int wid = tid >> 6;
    int lane = tid & 63;

    long long base = (long long)blockIdx.x * (TILES * 256);

    // FRONT-LOAD all 4 tiles of x (issued back-to-back; 4 outstanding vmem).
    f32x4 xv[TILES];
#pragma unroll
    for (int t = 0; t < TILES; ++t) {
        long long bt = base + (long long)t * 256 + tid;
        if (bt < nsamp) xv[t] = x[bt];
    }

    // Uniform monomial coefficients (SGPR), stages 0..3 = RY1, 4..7 = RY2.
    float w[8];
    int   ct[8];          // 1 = cot form (|s| > |c|), 0 = tan form
    float scale = 1.0f;
#pragma unroll
    for (int q = 0; q < 8; ++q) {
        float h = 0.5f * theta[q];
        float c = __cosf(h), s = __sinf(h);
        int cot = rfl(fabsf(s) > fabsf(c) ? 1 : 0);
        ct[q] = cot;
        w[q]  = rfl(cot ? (c / s) : (s / c));
        scale *= cot ? s : c;
    }
    scale = rfl(scale);

#pragma unroll
    for (int t = 0; t < TILES; ++t) {
        long long tileStart = base + (long long)t * 256;
        long long b = tileStart + tid;

        int p = t & 1;
        float* myBuf = sBuf[wid][p];

        if (b < nsamp) {
            // ---- per-qubit 2-vectors (amp bit q) ----
            float va[4], vb[4];
            if (b == 0) {
                // little-endian, raw probs, no sqrt: amp bit q <-> x qubit q
                va[0] = 1.0f - xv[t].x; vb[0] = xv[t].x;
                va[1] = 1.0f - xv[t].y; vb[1] = xv[t].y;
                va[2] = 1.0f - xv[t].z; vb[2] = xv[t].z;
                va[3] = 1.0f - xv[t].w; vb[3] = xv[t].w;
            } else {
                // big-endian, squared probs, sqrt: amp bit q <-> x qubit 3-q
                float p0 = xv[t].x * xv[t].x, p1 = xv[t].y * xv[t].y;
                float p2 = xv[t].z * xv[t].z, p3 = xv[t].w * xv[t].w;
                va[0] = FSQRT(1.0f - p3); vb[0] = FSQRT(p3);
                va[1] = FSQRT(1.0f - p2); vb[1] = FSQRT(p2);
                va[2] = FSQRT(1.0f - p1); vb[2] = FSQRT(p1);
                va[3] = FSQRT(1.0f - p0); vb[3] = FSQRT(p0);
            }

            // ---- RY1 fused: rotate each 2-vector (monomial, 2 FMA each) ----
#pragma unroll
            for (int q = 0; q < 4; ++q) {
                float A = va[q], B = vb[q];
                if (ct[q]) { va[q] = fmaf(w[q], A, -B); vb[q] = fmaf(w[q], B, A); }
                else       { va[q] = fmaf(-w[q], B, A); vb[q] = fmaf(w[q], A, B); }
            }

            // fold total uniform scale into qubit-3 vector
            va[3] *= scale; vb[3] *= scale;

            // ---- outer-product amp build ----
            float hi[4] = { va[3] * va[2], va[3] * vb[2],
                            vb[3] * va[2], vb[3] * vb[2] };
            float lo[4] = { va[1] * va[0], va[1] * vb[0],
                            vb[1] * va[0], vb[1] * vb[0] };
            float amp[16];
#pragma unroll
            for (int k = 0; k < 16; ++k)
                amp[k] = hi[k >> 2] * lo[k & 3];

            // D: sign flips at k = 3, 6, 9, 12
            amp[3]  = -amp[3];
            amp[6]  = -amp[6];
            amp[9]  = -amp[9];
            amp[12] = -amp[12];

            // ---- RY2 monomial butterflies (bits 0..2) ----
#define BFLY(Q, W, CT)                                                   \
            if (CT) {                                                    \
                _Pragma("unroll")                                        \
                for (int i0 = 0; i0 < 16; ++i0)                          \
                    if (!(i0 & (1 << (Q)))) {                            \
                        int i1 = i0 | (1 << (Q));                        \
                        float A = amp[i0], B = amp[i1];                  \
                        amp[i0] = fmaf((W), A, -B);                      \
                        amp[i1] = fmaf((W), B, A);                       \
                    }                                                    \
            } else {                                                     \
                _Pragma("unroll")                                        \
                for (int i0 = 0; i0 < 16; ++i0)                          \
                    if (!(i0 & (1 << (Q)))) {                            \
                        int i1 = i0 | (1 << (Q));                        \
                        float A = amp[i0], B = amp[i1];                  \
                        amp[i0] = fmaf(-(W), B, A);                      \
                        amp[i1] = fmaf((W), A, B);                       \
                    }                                                    \
            }

            BFLY(0, w[4], ct[4])
            BFLY(1, w[5], ct[5])
            BFLY(2, w[6], ct[6])
#undef BFLY

            // RY2 qubit-3 stage: only the 10 needed rows
            float r[10];
            if (ct[7]) {
#pragma unroll
                for (int i = 0; i < 8; ++i)
                    r[i] = fmaf(w[7], amp[i], -amp[i + 8]);
                r[8] = fmaf(w[7], amp[8], amp[0]);
                r[9] = fmaf(w[7], amp[9], amp[1]);
            } else {
#pragma unroll
                for (int i = 0; i < 8; ++i)
                    r[i] = fmaf(-w[7], amp[i + 8], amp[i]);
                r[8] = fmaf(w[7], amp[0], amp[8]);
                r[9] = fmaf(w[7], amp[1], amp[9]);
            }

#pragma unroll
            for (int c = 0; c < 10; ++c)
                myBuf[lane * 10 + c] = r[c] * r[c];   // 4-way bank alias: ~free
        }

        // drain OWN ds ops - intra-wave only, no barrier (wave-private slice)
        asm volatile("s_waitcnt lgkmcnt(0)" ::: "memory");

        long long waveBase = tileStart + (long long)(wid << 6);
        long long wrem = (long long)nsamp - waveBase;
        if (wrem >= 64) {
            // wave's 64 samples = 2560B contiguous in out, line-aligned.
            // NONTEMPORAL: out is write-once -> no-allocate, no L2/L3 churn.
            f32x4* ov = (f32x4*)(out + waveBase * 10);
            const f32x4* sv = (const f32x4*)myBuf;
#pragma unroll
            for (int i = lane; i < 160; i += 64)
                __builtin_nontemporal_store(sv[i], &ov[i]);
        } else if (wrem > 0) {
            int n = (int)wrem * 10;
            for (int i = lane; i < n; i += 64)
                out[waveBase * 10 + i] = myBuf[i];
        }
        // WAR on buffer p (reused at t+2): protected by the lgkmcnt(0) at
        // t+1, which drains this tile's flush ds_reads before t+2's writes.
    }
}

extern "C" void kernel_launch(void* const* d_in, const int* in_sizes, int n_in,
                              void* d_out, int out_size, void* d_ws, size_t ws_size,
                              hipStream_t stream) {
    const float* x = (const float*)d_in[0];      // [B,4] f32
    const float* theta = (const float*)d_in[1];  // [8]   f32
    float* out = (float*)d_out;                  // [B,10] f32

    int nsamp = in_sizes[0] / 4;
    int spb = TILES * 256;
    int blocks = (nsamp + spb - 1) / spb;
    vqc_main<<<blocks, 256, 0, stream>>>((const f32x4*)x, theta, out, nsamp);
}